// Round 1
// baseline (974.683 us; speedup 1.0000x reference)
//
#include <hip/hip_runtime.h>

// ---------------------------------------------------------------------------
// GPRGNN forward: h = x@W_in+b; hidden = t0*h; 4x { m = x@Wl+bl;
// agg = segsum(w * m[src], dst); x = relu(agg); hidden += t_i*x };
// out = hidden@W_out+b_out.
// Strategy: build CSR once per call (no fp32 atomics in hot path), fp32
// vector GEMMs (no fp32 MFMA on CDNA4), one-wave-per-node aggregation.
// ---------------------------------------------------------------------------

__global__ void hist_kernel(const int* __restrict__ dst, int* __restrict__ deg, int E) {
  int e = blockIdx.x * blockDim.x + threadIdx.x;
  if (e < E) atomicAdd(&deg[dst[e]], 1);
}

__global__ __launch_bounds__(1024) void scan_kernel(const int* __restrict__ deg,
                                                    int* __restrict__ rowptr,
                                                    int* __restrict__ cursor, int N) {
  __shared__ int s[1024];
  const int t = threadIdx.x;
  const int chunk = (N + 1023) >> 10;
  const int start = t * chunk;
  const int end = min(start + chunk, N);
  int sum = 0;
  for (int i = start; i < end; ++i) sum += deg[i];
  s[t] = sum;
  __syncthreads();
  // inclusive Hillis-Steele scan over 1024 partials
  for (int off = 1; off < 1024; off <<= 1) {
    int v = (t >= off) ? s[t - off] : 0;
    __syncthreads();
    s[t] += v;
    __syncthreads();
  }
  int run = (t == 0) ? 0 : s[t - 1];  // exclusive prefix of this chunk
  for (int i = start; i < end; ++i) {
    rowptr[i] = run;
    cursor[i] = run;
    run += deg[i];
  }
  if (t == 1023) rowptr[N] = s[1023];  // total == E
}

__global__ void fill_kernel(const int* __restrict__ src, const int* __restrict__ dst,
                            const float* __restrict__ w, int* __restrict__ cursor,
                            int* __restrict__ esrc, float* __restrict__ ew, int E) {
  int e = blockIdx.x * blockDim.x + threadIdx.x;
  if (e < E) {
    int d = dst[e];
    int p = atomicAdd(&cursor[d], 1);
    esrc[p] = src[e];
    ew[p] = w[e];
  }
}

__device__ __forceinline__ void fma4(float4& a, float s, const float4& w) {
  a.x = fmaf(s, w.x, a.x);
  a.y = fmaf(s, w.y, a.y);
  a.z = fmaf(s, w.z, a.z);
  a.w = fmaf(s, w.w, a.w);
}

// C[M][NCOL] = A[M][K] @ W[K][NCOL] + bias.  If hidden != nullptr also writes
// hidden = temp[0] * C (GPRGNN input-layer fusion).
// Thread block 256: CG=NCOL/8 col-groups x RG row-groups; thread computes
// 4 rows x 8 cols (two float4 col-slices at c*4 and NCOL/2+c*4 so wave LDS
// reads are <=2-way bank-aliased).  K tiled by 64 through LDS.
template <int NCOL>
__global__ __launch_bounds__(256) void gemm_f32(
    const float* __restrict__ A, const float* __restrict__ W,
    const float* __restrict__ bias, float* __restrict__ C,
    float* __restrict__ hidden, const float* __restrict__ temp, int M, int K) {
  constexpr int KT = 64;
  constexpr int CG = NCOL / 8;   // 16 (NCOL=128) or 8 (NCOL=64)
  constexpr int RG = 256 / CG;   // 16 or 32
  constexpr int MROWS = RG * 4;  // 64 or 128
  constexpr int XST = KT + 4;    // pad: stride 68 floats = 272B (16B aligned, 2-way banks)

  __shared__ float xs[MROWS * XST];
  __shared__ float wsh[KT * NCOL];

  const int tid = threadIdx.x;
  const int c = tid % CG;
  const int rg = tid / CG;
  const int blockRow = blockIdx.x * MROWS;

  float4 acc0[4], acc1[4];
#pragma unroll
  for (int r = 0; r < 4; ++r) {
    acc0[r] = make_float4(0.f, 0.f, 0.f, 0.f);
    acc1[r] = make_float4(0.f, 0.f, 0.f, 0.f);
  }

  for (int k0 = 0; k0 < K; k0 += KT) {
    __syncthreads();
    // stage A tile [MROWS][KT]
    for (int i = tid; i < MROWS * (KT / 4); i += 256) {
      int row = i >> 4;      // KT/4 == 16
      int kc = i & 15;
      float4 v = make_float4(0.f, 0.f, 0.f, 0.f);
      int grow = blockRow + row;
      if (grow < M)
        v = *reinterpret_cast<const float4*>(&A[(size_t)grow * K + k0 + kc * 4]);
      *reinterpret_cast<float4*>(&xs[row * XST + kc * 4]) = v;
    }
    // stage W tile [KT][NCOL]
    for (int i = tid; i < KT * (NCOL / 4); i += 256) {
      int kr = i / (NCOL / 4);
      int cc = i % (NCOL / 4);
      *reinterpret_cast<float4*>(&wsh[kr * NCOL + cc * 4]) =
          *reinterpret_cast<const float4*>(&W[(size_t)(k0 + kr) * NCOL + cc * 4]);
    }
    __syncthreads();

#pragma unroll
    for (int k = 0; k < KT; k += 4) {
      float4 av[4];
#pragma unroll
      for (int r = 0; r < 4; ++r)
        av[r] = *reinterpret_cast<const float4*>(&xs[(rg * 4 + r) * XST + k]);
      float4 w0[4], w1[4];
#pragma unroll
      for (int kk = 0; kk < 4; ++kk) {
        w0[kk] = *reinterpret_cast<const float4*>(&wsh[(k + kk) * NCOL + c * 4]);
        w1[kk] = *reinterpret_cast<const float4*>(&wsh[(k + kk) * NCOL + NCOL / 2 + c * 4]);
      }
#pragma unroll
      for (int r = 0; r < 4; ++r) {
        fma4(acc0[r], av[r].x, w0[0]);
        fma4(acc0[r], av[r].y, w0[1]);
        fma4(acc0[r], av[r].z, w0[2]);
        fma4(acc0[r], av[r].w, w0[3]);
        fma4(acc1[r], av[r].x, w1[0]);
        fma4(acc1[r], av[r].y, w1[1]);
        fma4(acc1[r], av[r].z, w1[2]);
        fma4(acc1[r], av[r].w, w1[3]);
      }
    }
  }

  // epilogue
  float4 b0 = *reinterpret_cast<const float4*>(&bias[c * 4]);
  float4 b1 = *reinterpret_cast<const float4*>(&bias[NCOL / 2 + c * 4]);
  float t0 = (hidden != nullptr) ? temp[0] : 0.f;
#pragma unroll
  for (int r = 0; r < 4; ++r) {
    int row = blockRow + rg * 4 + r;
    if (row >= M) continue;
    float4 v0 = acc0[r], v1 = acc1[r];
    v0.x += b0.x; v0.y += b0.y; v0.z += b0.z; v0.w += b0.w;
    v1.x += b1.x; v1.y += b1.y; v1.z += b1.z; v1.w += b1.w;
    size_t o0 = (size_t)row * NCOL + c * 4;
    size_t o1 = (size_t)row * NCOL + NCOL / 2 + c * 4;
    *reinterpret_cast<float4*>(&C[o0]) = v0;
    *reinterpret_cast<float4*>(&C[o1]) = v1;
    if (hidden != nullptr) {
      float4 h0 = make_float4(t0 * v0.x, t0 * v0.y, t0 * v0.z, t0 * v0.w);
      float4 h1 = make_float4(t0 * v1.x, t0 * v1.y, t0 * v1.z, t0 * v1.w);
      *reinterpret_cast<float4*>(&hidden[o0]) = h0;
      *reinterpret_cast<float4*>(&hidden[o1]) = h1;
    }
  }
}

// One wave per destination node. Lane l accumulates channels {2l, 2l+1}.
// Each edge: wave-uniform (esrc, ew) load + 512B coalesced gather of m[src].
// Fused epilogue: xnext = relu(agg); hidden += temp[idx] * xnext.
__global__ __launch_bounds__(256) void agg_kernel(
    const int* __restrict__ rowptr, const int* __restrict__ esrc,
    const float* __restrict__ ew, const float* __restrict__ m,
    float* __restrict__ xnext, float* __restrict__ hidden,
    const float* __restrict__ temp, int tempidx, int N) {
  int node = (int)((blockIdx.x * blockDim.x + threadIdx.x) >> 6);
  int lane = threadIdx.x & 63;
  if (node >= N) return;
  int beg = rowptr[node];
  int end = rowptr[node + 1];
  float ax = 0.f, ay = 0.f;
  for (int j = beg; j < end; ++j) {
    int s = esrc[j];    // wave-uniform
    float wt = ew[j];   // wave-uniform
    float2 v = *reinterpret_cast<const float2*>(&m[(size_t)s * 128 + lane * 2]);
    ax = fmaf(wt, v.x, ax);
    ay = fmaf(wt, v.y, ay);
  }
  float r0 = fmaxf(ax, 0.f);
  float r1 = fmaxf(ay, 0.f);
  size_t o = (size_t)node * 128 + lane * 2;
  *reinterpret_cast<float2*>(&xnext[o]) = make_float2(r0, r1);
  float tv = temp[tempidx];
  float2 h = *reinterpret_cast<const float2*>(&hidden[o]);
  h.x = fmaf(tv, r0, h.x);
  h.y = fmaf(tv, r1, h.y);
  *reinterpret_cast<float2*>(&hidden[o]) = h;
}

extern "C" void kernel_launch(void* const* d_in, const int* in_sizes, int n_in,
                              void* d_out, int out_size, void* d_ws, size_t ws_size,
                              hipStream_t stream) {
  const float* x     = (const float*)d_in[0];
  const float* w     = (const float*)d_in[1];
  const float* W_in  = (const float*)d_in[2];
  const float* b_in  = (const float*)d_in[3];
  const float* Wl    = (const float*)d_in[4];
  const float* bl    = (const float*)d_in[5];
  const float* temp  = (const float*)d_in[6];
  const float* W_out = (const float*)d_in[7];
  const float* b_out = (const float*)d_in[8];
  const int*   src   = (const int*)d_in[9];
  const int*   dst   = (const int*)d_in[10];

  const int IN = 512, H = 128, L = 4;
  const int N = in_sizes[0] / IN;   // 50000
  const int E = in_sizes[1];        // 800000

  // workspace carve (256B aligned)
  char* p = (char*)d_ws;
  auto alloc = [&](size_t bytes) {
    void* r = (void*)p;
    p += (bytes + 255) & ~(size_t)255;
    return r;
  };
  float* xcur   = (float*)alloc((size_t)N * H * sizeof(float));
  float* mbuf   = (float*)alloc((size_t)N * H * sizeof(float));
  float* hidden = (float*)alloc((size_t)N * H * sizeof(float));
  int*   deg    = (int*)alloc((size_t)N * sizeof(int));
  int*   rowptr = (int*)alloc((size_t)(N + 1) * sizeof(int));
  int*   cursor = (int*)alloc((size_t)N * sizeof(int));
  int*   esrc   = (int*)alloc((size_t)E * sizeof(int));
  float* ew     = (float*)alloc((size_t)E * sizeof(float));

  // ---- CSR build (once per call, reused by all 4 layers) ----
  hipMemsetAsync(deg, 0, (size_t)N * sizeof(int), stream);
  hist_kernel<<<(E + 255) / 256, 256, 0, stream>>>(dst, deg, E);
  scan_kernel<<<1, 1024, 0, stream>>>(deg, rowptr, cursor, N);
  fill_kernel<<<(E + 255) / 256, 256, 0, stream>>>(src, dst, w, cursor, esrc, ew, E);

  // ---- input projection: xcur = x@W_in + b_in; hidden = temp[0]*xcur ----
  gemm_f32<128><<<(N + 63) / 64, 256, 0, stream>>>(x, W_in, b_in, xcur, hidden, temp,
                                                   N, IN);

  // ---- 4 GPR layers ----
  for (int i = 0; i < L; ++i) {
    gemm_f32<128><<<(N + 63) / 64, 256, 0, stream>>>(
        xcur, Wl + (size_t)i * H * H, bl + (size_t)i * H, mbuf, nullptr, nullptr, N, H);
    agg_kernel<<<(N + 3) / 4, 256, 0, stream>>>(rowptr, esrc, ew, mbuf, xcur, hidden,
                                                temp, i + 1, N);
  }

  // ---- output projection ----
  gemm_f32<64><<<(N + 127) / 128, 256, 0, stream>>>(hidden, W_out, b_out, (float*)d_out,
                                                    nullptr, nullptr, N, H);
}

// Round 2
// 840.890 us; speedup vs baseline: 1.1591x; 1.1591x over previous
//
#include <hip/hip_runtime.h>

// ---------------------------------------------------------------------------
// GPRGNN forward. R2 changes vs R1:
//  1. agg_kernel: edge loop unrolled x4 with independent accumulators ->
//     4 outstanding 512B gathers per wave (was 1; latency-bound at 3.2 TB/s).
//  2. gemm_f32: global->LDS staging via __builtin_amdgcn_global_load_lds
//     (width 16), linear un-padded A tile (gll needs contiguous dest).
// ---------------------------------------------------------------------------

__global__ void hist_kernel(const int* __restrict__ dst, int* __restrict__ deg, int E) {
  int e = blockIdx.x * blockDim.x + threadIdx.x;
  if (e < E) atomicAdd(&deg[dst[e]], 1);
}

__global__ __launch_bounds__(1024) void scan_kernel(const int* __restrict__ deg,
                                                    int* __restrict__ rowptr,
                                                    int* __restrict__ cursor, int N) {
  __shared__ int s[1024];
  const int t = threadIdx.x;
  const int chunk = (N + 1023) >> 10;
  const int start = t * chunk;
  const int end = min(start + chunk, N);
  int sum = 0;
  for (int i = start; i < end; ++i) sum += deg[i];
  s[t] = sum;
  __syncthreads();
  for (int off = 1; off < 1024; off <<= 1) {
    int v = (t >= off) ? s[t - off] : 0;
    __syncthreads();
    s[t] += v;
    __syncthreads();
  }
  int run = (t == 0) ? 0 : s[t - 1];
  for (int i = start; i < end; ++i) {
    rowptr[i] = run;
    cursor[i] = run;
    run += deg[i];
  }
  if (t == 1023) rowptr[N] = s[1023];
}

__global__ void fill_kernel(const int* __restrict__ src, const int* __restrict__ dst,
                            const float* __restrict__ w, int* __restrict__ cursor,
                            int* __restrict__ esrc, float* __restrict__ ew, int E) {
  int e = blockIdx.x * blockDim.x + threadIdx.x;
  if (e < E) {
    int d = dst[e];
    int p = atomicAdd(&cursor[d], 1);
    esrc[p] = src[e];
    ew[p] = w[e];
  }
}

__device__ __forceinline__ void fma4(float4& a, float s, const float4& w) {
  a.x = fmaf(s, w.x, a.x);
  a.y = fmaf(s, w.y, a.y);
  a.z = fmaf(s, w.z, a.z);
  a.w = fmaf(s, w.w, a.w);
}

// async global->LDS, 16B per lane (lds dest = wave-uniform base + lane*16)
__device__ __forceinline__ void gll16(const void* g, void* l) {
  __builtin_amdgcn_global_load_lds(
      (const __attribute__((address_space(1))) unsigned int*)g,
      (__attribute__((address_space(3))) unsigned int*)l, 16, 0, 0);
}

// C[M][NCOL] = A[M][K] @ W[K][NCOL] + bias; optional hidden = temp[0]*C.
// 256 threads: CG=NCOL/8 col-groups x RG row-groups, thread = 4 rows x 8 cols
// (two float4 slices at c*4 and NCOL/2+c*4). K tiled by 64 through LDS,
// staged with global_load_lds (linear tiles, no padding).
template <int NCOL>
__global__ __launch_bounds__(256) void gemm_f32(
    const float* __restrict__ A, const float* __restrict__ W,
    const float* __restrict__ bias, float* __restrict__ C,
    float* __restrict__ hidden, const float* __restrict__ temp, int M, int K) {
  constexpr int KT = 64;
  constexpr int CG = NCOL / 8;       // 16 (NCOL=128) or 8 (NCOL=64)
  constexpr int RG = 256 / CG;       // 16 or 32
  constexpr int MROWS = RG * 4;      // 64 or 128
  constexpr int ACH = MROWS / 4;     // A chunks of 1024B (row = 256B)
  constexpr int WCH = NCOL / 4;      // W chunks of 1024B

  __shared__ float xs[MROWS * KT];   // linear [row][k], 256B rows
  __shared__ float wsh[KT * NCOL];   // linear [k][col]

  const int tid = threadIdx.x;
  const int lane = tid & 63;
  const int wave = tid >> 6;
  const int c = tid % CG;
  const int rg = tid / CG;
  const int blockRow = blockIdx.x * MROWS;

  float4 acc0[4], acc1[4];
#pragma unroll
  for (int r = 0; r < 4; ++r) {
    acc0[r] = make_float4(0.f, 0.f, 0.f, 0.f);
    acc1[r] = make_float4(0.f, 0.f, 0.f, 0.f);
  }

  for (int k0 = 0; k0 < K; k0 += KT) {
    __syncthreads();
    // stage A tile [MROWS][KT] fp32 — 1024B per wave-call (4 rows)
    for (int ch = wave; ch < ACH; ch += 4) {
      int b = ch * 1024 + lane * 16;
      int row = b >> 8;
      int kb = b & 255;
      int grow = blockRow + row;
      if (grow >= M) grow = M - 1;  // clamp: valid memory, result discarded
      gll16(&A[(size_t)grow * K + k0 + (kb >> 2)], (char*)xs + (size_t)ch * 1024);
    }
    // stage W tile [KT][NCOL]
    for (int ch = wave; ch < WCH; ch += 4) {
      int b = ch * 1024 + lane * 16;
      int kr = b / (NCOL * 4);
      int cb = b % (NCOL * 4);
      gll16(&W[(size_t)(k0 + kr) * NCOL + (cb >> 2)], (char*)wsh + (size_t)ch * 1024);
    }
    __syncthreads();  // drains vmcnt -> tiles ready

#pragma unroll
    for (int k = 0; k < KT; k += 4) {
      float4 av[4];
#pragma unroll
      for (int r = 0; r < 4; ++r)
        av[r] = *reinterpret_cast<const float4*>(&xs[(rg * 4 + r) * KT + k]);
      float4 w0[4], w1[4];
#pragma unroll
      for (int kk = 0; kk < 4; ++kk) {
        w0[kk] = *reinterpret_cast<const float4*>(&wsh[(k + kk) * NCOL + c * 4]);
        w1[kk] = *reinterpret_cast<const float4*>(&wsh[(k + kk) * NCOL + NCOL / 2 + c * 4]);
      }
#pragma unroll
      for (int r = 0; r < 4; ++r) {
        fma4(acc0[r], av[r].x, w0[0]);
        fma4(acc0[r], av[r].y, w0[1]);
        fma4(acc0[r], av[r].z, w0[2]);
        fma4(acc0[r], av[r].w, w0[3]);
        fma4(acc1[r], av[r].x, w1[0]);
        fma4(acc1[r], av[r].y, w1[1]);
        fma4(acc1[r], av[r].z, w1[2]);
        fma4(acc1[r], av[r].w, w1[3]);
      }
    }
  }

  float4 b0 = *reinterpret_cast<const float4*>(&bias[c * 4]);
  float4 b1 = *reinterpret_cast<const float4*>(&bias[NCOL / 2 + c * 4]);
  float t0 = (hidden != nullptr) ? temp[0] : 0.f;
#pragma unroll
  for (int r = 0; r < 4; ++r) {
    int row = blockRow + rg * 4 + r;
    if (row >= M) continue;
    float4 v0 = acc0[r], v1 = acc1[r];
    v0.x += b0.x; v0.y += b0.y; v0.z += b0.z; v0.w += b0.w;
    v1.x += b1.x; v1.y += b1.y; v1.z += b1.z; v1.w += b1.w;
    size_t o0 = (size_t)row * NCOL + c * 4;
    size_t o1 = (size_t)row * NCOL + NCOL / 2 + c * 4;
    *reinterpret_cast<float4*>(&C[o0]) = v0;
    *reinterpret_cast<float4*>(&C[o1]) = v1;
    if (hidden != nullptr) {
      float4 h0 = make_float4(t0 * v0.x, t0 * v0.y, t0 * v0.z, t0 * v0.w);
      float4 h1 = make_float4(t0 * v1.x, t0 * v1.y, t0 * v1.z, t0 * v1.w);
      *reinterpret_cast<float4*>(&hidden[o0]) = h0;
      *reinterpret_cast<float4*>(&hidden[o1]) = h1;
    }
  }
}

// One wave per destination node, lane l owns channels {2l,2l+1}.
// Edge loop unrolled x4 with independent accumulators -> 4 outstanding
// 512B wave-gathers (memory-level parallelism; was latency-serialized).
__global__ __launch_bounds__(256) void agg_kernel(
    const int* __restrict__ rowptr, const int* __restrict__ esrc,
    const float* __restrict__ ew, const float* __restrict__ m,
    float* __restrict__ xnext, float* __restrict__ hidden,
    const float* __restrict__ temp, int tempidx, int N) {
  int node = (int)((blockIdx.x * blockDim.x + threadIdx.x) >> 6);
  int lane = threadIdx.x & 63;
  if (node >= N) return;
  int beg = rowptr[node];
  int end = rowptr[node + 1];
  float ax0 = 0.f, ay0 = 0.f, ax1 = 0.f, ay1 = 0.f;
  float ax2 = 0.f, ay2 = 0.f, ax3 = 0.f, ay3 = 0.f;
  int j = beg;
  for (; j + 4 <= end; j += 4) {
    int s0 = esrc[j], s1 = esrc[j + 1], s2 = esrc[j + 2], s3 = esrc[j + 3];
    float w0 = ew[j], w1 = ew[j + 1], w2 = ew[j + 2], w3 = ew[j + 3];
    float2 v0 = *reinterpret_cast<const float2*>(&m[(size_t)s0 * 128 + lane * 2]);
    float2 v1 = *reinterpret_cast<const float2*>(&m[(size_t)s1 * 128 + lane * 2]);
    float2 v2 = *reinterpret_cast<const float2*>(&m[(size_t)s2 * 128 + lane * 2]);
    float2 v3 = *reinterpret_cast<const float2*>(&m[(size_t)s3 * 128 + lane * 2]);
    ax0 = fmaf(w0, v0.x, ax0); ay0 = fmaf(w0, v0.y, ay0);
    ax1 = fmaf(w1, v1.x, ax1); ay1 = fmaf(w1, v1.y, ay1);
    ax2 = fmaf(w2, v2.x, ax2); ay2 = fmaf(w2, v2.y, ay2);
    ax3 = fmaf(w3, v3.x, ax3); ay3 = fmaf(w3, v3.y, ay3);
  }
  for (; j < end; ++j) {
    int s = esrc[j];
    float wt = ew[j];
    float2 v = *reinterpret_cast<const float2*>(&m[(size_t)s * 128 + lane * 2]);
    ax0 = fmaf(wt, v.x, ax0);
    ay0 = fmaf(wt, v.y, ay0);
  }
  float ax = (ax0 + ax1) + (ax2 + ax3);
  float ay = (ay0 + ay1) + (ay2 + ay3);
  float r0 = fmaxf(ax, 0.f);
  float r1 = fmaxf(ay, 0.f);
  size_t o = (size_t)node * 128 + lane * 2;
  *reinterpret_cast<float2*>(&xnext[o]) = make_float2(r0, r1);
  float tv = temp[tempidx];
  float2 h = *reinterpret_cast<const float2*>(&hidden[o]);
  h.x = fmaf(tv, r0, h.x);
  h.y = fmaf(tv, r1, h.y);
  *reinterpret_cast<float2*>(&hidden[o]) = h;
}

extern "C" void kernel_launch(void* const* d_in, const int* in_sizes, int n_in,
                              void* d_out, int out_size, void* d_ws, size_t ws_size,
                              hipStream_t stream) {
  const float* x     = (const float*)d_in[0];
  const float* w     = (const float*)d_in[1];
  const float* W_in  = (const float*)d_in[2];
  const float* b_in  = (const float*)d_in[3];
  const float* Wl    = (const float*)d_in[4];
  const float* bl    = (const float*)d_in[5];
  const float* temp  = (const float*)d_in[6];
  const float* W_out = (const float*)d_in[7];
  const float* b_out = (const float*)d_in[8];
  const int*   src   = (const int*)d_in[9];
  const int*   dst   = (const int*)d_in[10];

  const int IN = 512, H = 128, L = 4;
  const int N = in_sizes[0] / IN;   // 50000
  const int E = in_sizes[1];        // 800000

  char* p = (char*)d_ws;
  auto alloc = [&](size_t bytes) {
    void* r = (void*)p;
    p += (bytes + 255) & ~(size_t)255;
    return r;
  };
  float* xcur   = (float*)alloc((size_t)N * H * sizeof(float));
  float* mbuf   = (float*)alloc((size_t)N * H * sizeof(float));
  float* hidden = (float*)alloc((size_t)N * H * sizeof(float));
  int*   deg    = (int*)alloc((size_t)N * sizeof(int));
  int*   rowptr = (int*)alloc((size_t)(N + 1) * sizeof(int));
  int*   cursor = (int*)alloc((size_t)N * sizeof(int));
  int*   esrc   = (int*)alloc((size_t)E * sizeof(int));
  float* ew     = (float*)alloc((size_t)E * sizeof(float));

  // ---- CSR build (once per call) ----
  hipMemsetAsync(deg, 0, (size_t)N * sizeof(int), stream);
  hist_kernel<<<(E + 255) / 256, 256, 0, stream>>>(dst, deg, E);
  scan_kernel<<<1, 1024, 0, stream>>>(deg, rowptr, cursor, N);
  fill_kernel<<<(E + 255) / 256, 256, 0, stream>>>(src, dst, w, cursor, esrc, ew, E);

  // ---- input projection ----
  gemm_f32<128><<<(N + 63) / 64, 256, 0, stream>>>(x, W_in, b_in, xcur, hidden, temp,
                                                   N, IN);

  // ---- 4 GPR layers ----
  for (int i = 0; i < L; ++i) {
    gemm_f32<128><<<(N + 63) / 64, 256, 0, stream>>>(
        xcur, Wl + (size_t)i * H * H, bl + (size_t)i * H, mbuf, nullptr, nullptr, N, H);
    agg_kernel<<<(N + 3) / 4, 256, 0, stream>>>(rowptr, esrc, ew, mbuf, xcur, hidden,
                                                temp, i + 1, N);
  }

  // ---- output projection ----
  gemm_f32<64><<<(N + 127) / 128, 256, 0, stream>>>(hidden, W_out, b_out, (float*)d_out,
                                                    nullptr, nullptr, N, H);
}

// Round 3
// 642.731 us; speedup vs baseline: 1.5165x; 1.3083x over previous
//
#include <hip/hip_runtime.h>

// ---------------------------------------------------------------------------
// GPRGNN forward. R3 changes vs R2:
//  1. All H=128 GEMMs -> bf16 MFMA (16x16x32, m97 geometry: 128x128 tile,
//     BK=32, 4 waves 2x2, gll16 staging). Input GEMM fuses fp32->bf16
//     conversion into A staging. Weights transposed+converted once per call.
//  2. Messages (mbuf) and xcur stored bf16 -> gather traffic halves.
//  3. CSR build + fp32 out-GEMM unchanged.
// ---------------------------------------------------------------------------

typedef __attribute__((ext_vector_type(8))) short short8;
typedef __attribute__((ext_vector_type(4))) float f32x4;

__device__ __forceinline__ unsigned short f2bf(float f) {
  union { float f; unsigned u; } c{f};
  unsigned u = c.u;
  return (unsigned short)((u + 0x7fff + ((u >> 16) & 1)) >> 16);  // RNE
}
__device__ __forceinline__ float bf2f_lo(unsigned v) {
  return __uint_as_float(v << 16);
}
__device__ __forceinline__ float bf2f_hi(unsigned v) {
  return __uint_as_float(v & 0xffff0000u);
}
__device__ __forceinline__ unsigned pack2bf(float a, float b) {
  return (unsigned)f2bf(a) | ((unsigned)f2bf(b) << 16);
}

// async global->LDS, 16B per lane (lds dest = wave-uniform base + lane*16)
__device__ __forceinline__ void gll16(const void* g, void* l) {
  __builtin_amdgcn_global_load_lds(
      (const __attribute__((address_space(1))) unsigned int*)g,
      (__attribute__((address_space(3))) unsigned int*)l, 16, 0, 0);
}

// ---------------- CSR build ----------------
__global__ void hist_kernel(const int* __restrict__ dst, int* __restrict__ deg, int E) {
  int e = blockIdx.x * blockDim.x + threadIdx.x;
  if (e < E) atomicAdd(&deg[dst[e]], 1);
}

__global__ __launch_bounds__(1024) void scan_kernel(const int* __restrict__ deg,
                                                    int* __restrict__ rowptr,
                                                    int* __restrict__ cursor, int N) {
  __shared__ int s[1024];
  const int t = threadIdx.x;
  const int chunk = (N + 1023) >> 10;
  const int start = t * chunk;
  const int end = min(start + chunk, N);
  int sum = 0;
  for (int i = start; i < end; ++i) sum += deg[i];
  s[t] = sum;
  __syncthreads();
  for (int off = 1; off < 1024; off <<= 1) {
    int v = (t >= off) ? s[t - off] : 0;
    __syncthreads();
    s[t] += v;
    __syncthreads();
  }
  int run = (t == 0) ? 0 : s[t - 1];
  for (int i = start; i < end; ++i) {
    rowptr[i] = run;
    cursor[i] = run;
    run += deg[i];
  }
  if (t == 1023) rowptr[N] = s[1023];
}

__global__ void fill_kernel(const int* __restrict__ src, const int* __restrict__ dst,
                            const float* __restrict__ w, int* __restrict__ cursor,
                            int* __restrict__ esrc, float* __restrict__ ew, int E) {
  int e = blockIdx.x * blockDim.x + threadIdx.x;
  if (e < E) {
    int d = dst[e];
    int p = atomicAdd(&cursor[d], 1);
    esrc[p] = src[e];
    ew[p] = w[e];
  }
}

// ---------------- weight convert + transpose (once per call, tiny) ----------
// WinT[n][k] = bf16(W_in[k][n])  (128 x 512)
// WlT[l][n][k] = bf16(Wl[l][k][n]) (4 x 128 x 128)
__global__ void conv_w_kernel(const float* __restrict__ W_in,
                              const float* __restrict__ Wl,
                              unsigned short* __restrict__ WinT,
                              unsigned short* __restrict__ WlT) {
  int o = blockIdx.x * blockDim.x + threadIdx.x;
  if (o < 65536) {
    int n = o >> 9, k = o & 511;
    WinT[o] = f2bf(W_in[k * 128 + n]);
  } else if (o < 131072) {
    int p = o - 65536;
    int layer = p >> 14, n = (p >> 7) & 127, k = p & 127;
    WlT[p] = f2bf(Wl[layer * 16384 + k * 128 + n]);
  }
}

// ---------------- bf16 MFMA GEMM: C[M][128] = A[M][K] @ B[K][128] + bias ----
// m97 geometry: block 256 (4 waves, 2x2), tile 128x128, BK=32.
// A frag: lane holds A[m = l&15][k = (l>>4)*8 + 0..7]; B frag from BT[n][k]
// same pattern. acc C/D: row=(l>>4)*4+r, col=l&15 (HW-verified layout).
// CONV: A is fp32, converted to bf16 during LDS staging (input layer).
// INMODE: also writes hidden = temp[0]*C as fp32.
template <int K, bool CONV, bool INMODE>
__global__ __launch_bounds__(256) void gemm_bf16(
    const void* __restrict__ Ain, const unsigned short* __restrict__ BT,
    const float* __restrict__ bias, unsigned short* __restrict__ Cb,
    float* __restrict__ hidden, const float* __restrict__ temp, int M) {
  __shared__ unsigned short As[128 * 32];  // [m][k] 8 KB
  __shared__ unsigned short Bs[128 * 32];  // [n][k] 8 KB

  const int tid = threadIdx.x;
  const int lane = tid & 63;
  const int wave = tid >> 6;
  const int wm = (wave & 1) * 64;
  const int wn = (wave >> 1) * 64;
  const int blockRow = blockIdx.x * 128;

  f32x4 acc[4][4];
#pragma unroll
  for (int i = 0; i < 4; ++i)
#pragma unroll
    for (int j = 0; j < 4; ++j) acc[i][j] = (f32x4){0.f, 0.f, 0.f, 0.f};

  for (int k0 = 0; k0 < K; k0 += 32) {
    __syncthreads();
    if (CONV) {
      // fp32 A: 256 threads x 16 floats; 2 threads per tile row
      const float* A = (const float*)Ain;
      int row = tid >> 1;
      int kc = (tid & 1) * 16;
      int grow = blockRow + row;
      if (grow >= M) grow = M - 1;
      const float* s = &A[(size_t)grow * K + k0 + kc];
      float4 v0 = *(const float4*)(s);
      float4 v1 = *(const float4*)(s + 4);
      float4 v2 = *(const float4*)(s + 8);
      float4 v3 = *(const float4*)(s + 12);
      uint4 p0, p1;
      p0.x = pack2bf(v0.x, v0.y); p0.y = pack2bf(v0.z, v0.w);
      p0.z = pack2bf(v1.x, v1.y); p0.w = pack2bf(v1.z, v1.w);
      p1.x = pack2bf(v2.x, v2.y); p1.y = pack2bf(v2.z, v2.w);
      p1.z = pack2bf(v3.x, v3.y); p1.w = pack2bf(v3.z, v3.w);
      *(uint4*)&As[row * 32 + kc] = p0;
      *(uint4*)&As[row * 32 + kc + 8] = p1;
    } else {
      // bf16 A: gll16, 8 chunks of 1024B (16 rows x 64B)
      const unsigned short* A = (const unsigned short*)Ain;
#pragma unroll
      for (int ch = wave; ch < 8; ch += 4) {
        int row = ch * 16 + (lane >> 2);
        int grow = blockRow + row;
        if (grow >= M) grow = M - 1;
        gll16(&A[(size_t)grow * K + k0 + (lane & 3) * 8], (char*)As + ch * 1024);
      }
    }
    // B tile: BT[n][k], rows always valid (128 n-rows)
#pragma unroll
    for (int ch = wave; ch < 8; ch += 4) {
      int row = ch * 16 + (lane >> 2);
      gll16(&BT[(size_t)row * K + k0 + (lane & 3) * 8], (char*)Bs + ch * 1024);
    }
    __syncthreads();

    short8 af[4], bfr[4];
#pragma unroll
    for (int i = 0; i < 4; ++i)
      af[i] = *(const short8*)&As[(wm + i * 16 + (lane & 15)) * 32 + (lane >> 4) * 8];
#pragma unroll
    for (int j = 0; j < 4; ++j)
      bfr[j] = *(const short8*)&Bs[(wn + j * 16 + (lane & 15)) * 32 + (lane >> 4) * 8];
#pragma unroll
    for (int i = 0; i < 4; ++i)
#pragma unroll
      for (int j = 0; j < 4; ++j)
        acc[i][j] =
            __builtin_amdgcn_mfma_f32_16x16x32_bf16(af[i], bfr[j], acc[i][j], 0, 0, 0);
  }

  // epilogue: D row=(l>>4)*4+r, col=l&15
  float t0 = INMODE ? temp[0] : 0.f;
#pragma unroll
  for (int j = 0; j < 4; ++j) {
    int col = wn + j * 16 + (lane & 15);
    float bj = bias[col];
#pragma unroll
    for (int i = 0; i < 4; ++i) {
#pragma unroll
      for (int r = 0; r < 4; ++r) {
        int row = blockRow + wm + i * 16 + (lane >> 4) * 4 + r;
        if (row < M) {
          float v = acc[i][j][r] + bj;
          Cb[(size_t)row * 128 + col] = f2bf(v);
          if (INMODE) hidden[(size_t)row * 128 + col] = t0 * v;
        }
      }
    }
  }
}

// ---------------- aggregation: one wave per node, bf16 messages -------------
// lane l owns channels {2l, 2l+1} (one packed dword per edge). Unroll x4 for
// memory-level parallelism. Accumulate fp32; write xnext bf16 + hidden fp32.
__global__ __launch_bounds__(256) void agg_bf16(
    const int* __restrict__ rowptr, const int* __restrict__ esrc,
    const float* __restrict__ ew, const unsigned short* __restrict__ mb,
    unsigned short* __restrict__ xnext, float* __restrict__ hidden,
    const float* __restrict__ temp, int tempidx, int N) {
  int node = (int)((blockIdx.x * blockDim.x + threadIdx.x) >> 6);
  int lane = threadIdx.x & 63;
  if (node >= N) return;
  int beg = rowptr[node];
  int end = rowptr[node + 1];
  float ax0 = 0.f, ay0 = 0.f, ax1 = 0.f, ay1 = 0.f;
  float ax2 = 0.f, ay2 = 0.f, ax3 = 0.f, ay3 = 0.f;
  int j = beg;
  for (; j + 4 <= end; j += 4) {
    int s0 = esrc[j], s1 = esrc[j + 1], s2 = esrc[j + 2], s3 = esrc[j + 3];
    float w0 = ew[j], w1 = ew[j + 1], w2 = ew[j + 2], w3 = ew[j + 3];
    unsigned v0 = *(const unsigned*)&mb[(size_t)s0 * 128 + lane * 2];
    unsigned v1 = *(const unsigned*)&mb[(size_t)s1 * 128 + lane * 2];
    unsigned v2 = *(const unsigned*)&mb[(size_t)s2 * 128 + lane * 2];
    unsigned v3 = *(const unsigned*)&mb[(size_t)s3 * 128 + lane * 2];
    ax0 = fmaf(w0, bf2f_lo(v0), ax0); ay0 = fmaf(w0, bf2f_hi(v0), ay0);
    ax1 = fmaf(w1, bf2f_lo(v1), ax1); ay1 = fmaf(w1, bf2f_hi(v1), ay1);
    ax2 = fmaf(w2, bf2f_lo(v2), ax2); ay2 = fmaf(w2, bf2f_hi(v2), ay2);
    ax3 = fmaf(w3, bf2f_lo(v3), ax3); ay3 = fmaf(w3, bf2f_hi(v3), ay3);
  }
  for (; j < end; ++j) {
    int s = esrc[j];
    float wt = ew[j];
    unsigned v = *(const unsigned*)&mb[(size_t)s * 128 + lane * 2];
    ax0 = fmaf(wt, bf2f_lo(v), ax0);
    ay0 = fmaf(wt, bf2f_hi(v), ay0);
  }
  float ax = (ax0 + ax1) + (ax2 + ax3);
  float ay = (ay0 + ay1) + (ay2 + ay3);
  float r0 = fmaxf(ax, 0.f);
  float r1 = fmaxf(ay, 0.f);
  size_t o = (size_t)node * 128 + lane * 2;
  *(unsigned*)&xnext[o] = pack2bf(r0, r1);
  float tv = temp[tempidx];
  float2 h = *reinterpret_cast<const float2*>(&hidden[o]);
  h.x = fmaf(tv, r0, h.x);
  h.y = fmaf(tv, r1, h.y);
  *reinterpret_cast<float2*>(&hidden[o]) = h;
}

// ---------------- fp32 vector GEMM (output projection only) -----------------
__device__ __forceinline__ void fma4(float4& a, float s, const float4& w) {
  a.x = fmaf(s, w.x, a.x);
  a.y = fmaf(s, w.y, a.y);
  a.z = fmaf(s, w.z, a.z);
  a.w = fmaf(s, w.w, a.w);
}

template <int NCOL>
__global__ __launch_bounds__(256) void gemm_f32(
    const float* __restrict__ A, const float* __restrict__ W,
    const float* __restrict__ bias, float* __restrict__ C, int M, int K) {
  constexpr int KT = 64;
  constexpr int CG = NCOL / 8;
  constexpr int RG = 256 / CG;
  constexpr int MROWS = RG * 4;
  constexpr int ACH = MROWS / 4;
  constexpr int WCH = NCOL / 4;

  __shared__ float xs[MROWS * KT];
  __shared__ float wsh[KT * NCOL];

  const int tid = threadIdx.x;
  const int lane = tid & 63;
  const int wave = tid >> 6;
  const int c = tid % CG;
  const int rg = tid / CG;
  const int blockRow = blockIdx.x * MROWS;

  float4 acc0[4], acc1[4];
#pragma unroll
  for (int r = 0; r < 4; ++r) {
    acc0[r] = make_float4(0.f, 0.f, 0.f, 0.f);
    acc1[r] = make_float4(0.f, 0.f, 0.f, 0.f);
  }

  for (int k0 = 0; k0 < K; k0 += KT) {
    __syncthreads();
    for (int ch = wave; ch < ACH; ch += 4) {
      int b = ch * 1024 + lane * 16;
      int row = b >> 8;
      int kb = b & 255;
      int grow = blockRow + row;
      if (grow >= M) grow = M - 1;
      gll16(&A[(size_t)grow * K + k0 + (kb >> 2)], (char*)xs + (size_t)ch * 1024);
    }
    for (int ch = wave; ch < WCH; ch += 4) {
      int b = ch * 1024 + lane * 16;
      int kr = b / (NCOL * 4);
      int cb = b % (NCOL * 4);
      gll16(&W[(size_t)(k0 + kr) * NCOL + (cb >> 2)], (char*)wsh + (size_t)ch * 1024);
    }
    __syncthreads();

#pragma unroll
    for (int k = 0; k < KT; k += 4) {
      float4 av[4];
#pragma unroll
      for (int r = 0; r < 4; ++r)
        av[r] = *reinterpret_cast<const float4*>(&xs[(rg * 4 + r) * KT + k]);
      float4 w0[4], w1[4];
#pragma unroll
      for (int kk = 0; kk < 4; ++kk) {
        w0[kk] = *reinterpret_cast<const float4*>(&wsh[(k + kk) * NCOL + c * 4]);
        w1[kk] = *reinterpret_cast<const float4*>(&wsh[(k + kk) * NCOL + NCOL / 2 + c * 4]);
      }
#pragma unroll
      for (int r = 0; r < 4; ++r) {
        fma4(acc0[r], av[r].x, w0[0]);
        fma4(acc0[r], av[r].y, w0[1]);
        fma4(acc0[r], av[r].z, w0[2]);
        fma4(acc0[r], av[r].w, w0[3]);
        fma4(acc1[r], av[r].x, w1[0]);
        fma4(acc1[r], av[r].y, w1[1]);
        fma4(acc1[r], av[r].z, w1[2]);
        fma4(acc1[r], av[r].w, w1[3]);
      }
    }
  }

  float4 b0 = *reinterpret_cast<const float4*>(&bias[c * 4]);
  float4 b1 = *reinterpret_cast<const float4*>(&bias[NCOL / 2 + c * 4]);
#pragma unroll
  for (int r = 0; r < 4; ++r) {
    int row = blockRow + rg * 4 + r;
    if (row >= M) continue;
    float4 v0 = acc0[r], v1 = acc1[r];
    v0.x += b0.x; v0.y += b0.y; v0.z += b0.z; v0.w += b0.w;
    v1.x += b1.x; v1.y += b1.y; v1.z += b1.z; v1.w += b1.w;
    *reinterpret_cast<float4*>(&C[(size_t)row * NCOL + c * 4]) = v0;
    *reinterpret_cast<float4*>(&C[(size_t)row * NCOL + NCOL / 2 + c * 4]) = v1;
  }
}

extern "C" void kernel_launch(void* const* d_in, const int* in_sizes, int n_in,
                              void* d_out, int out_size, void* d_ws, size_t ws_size,
                              hipStream_t stream) {
  const float* x     = (const float*)d_in[0];
  const float* w     = (const float*)d_in[1];
  const float* W_in  = (const float*)d_in[2];
  const float* b_in  = (const float*)d_in[3];
  const float* Wl    = (const float*)d_in[4];
  const float* bl    = (const float*)d_in[5];
  const float* temp  = (const float*)d_in[6];
  const float* W_out = (const float*)d_in[7];
  const float* b_out = (const float*)d_in[8];
  const int*   src   = (const int*)d_in[9];
  const int*   dst   = (const int*)d_in[10];

  const int IN = 512, H = 128, L = 4;
  const int N = in_sizes[0] / IN;   // 50000
  const int E = in_sizes[1];        // 800000

  char* p = (char*)d_ws;
  auto alloc = [&](size_t bytes) {
    void* r = (void*)p;
    p += (bytes + 255) & ~(size_t)255;
    return r;
  };
  unsigned short* xcur_b = (unsigned short*)alloc((size_t)N * H * 2);
  unsigned short* mbuf_b = (unsigned short*)alloc((size_t)N * H * 2);
  float* hidden          = (float*)alloc((size_t)N * H * sizeof(float));
  unsigned short* WinT   = (unsigned short*)alloc((size_t)H * IN * 2);
  unsigned short* WlT    = (unsigned short*)alloc((size_t)L * H * H * 2);
  int*   deg    = (int*)alloc((size_t)N * sizeof(int));
  int*   rowptr = (int*)alloc((size_t)(N + 1) * sizeof(int));
  int*   cursor = (int*)alloc((size_t)N * sizeof(int));
  int*   esrc   = (int*)alloc((size_t)E * sizeof(int));
  float* ew     = (float*)alloc((size_t)E * sizeof(float));

  // ---- CSR build + weight conversion (once per call) ----
  hipMemsetAsync(deg, 0, (size_t)N * sizeof(int), stream);
  hist_kernel<<<(E + 255) / 256, 256, 0, stream>>>(dst, deg, E);
  scan_kernel<<<1, 1024, 0, stream>>>(deg, rowptr, cursor, N);
  fill_kernel<<<(E + 255) / 256, 256, 0, stream>>>(src, dst, w, cursor, esrc, ew, E);
  conv_w_kernel<<<512, 256, 0, stream>>>(W_in, Wl, WinT, WlT);

  const int gB = (N + 127) / 128;  // 391

  // ---- input projection (fused fp32->bf16 conversion of x) ----
  gemm_bf16<512, true, true><<<gB, 256, 0, stream>>>(x, WinT, b_in, xcur_b, hidden,
                                                     temp, N);

  // ---- 4 GPR layers ----
  for (int i = 0; i < L; ++i) {
    gemm_bf16<128, false, false><<<gB, 256, 0, stream>>>(
        xcur_b, WlT + (size_t)i * H * H, bl + (size_t)i * H, mbuf_b, nullptr, temp, N);
    agg_bf16<<<(N + 3) / 4, 256, 0, stream>>>(rowptr, esrc, ew, mbuf_b, xcur_b, hidden,
                                              temp, i + 1, N);
  }

  // ---- output projection (fp32 vector) ----
  gemm_f32<64><<<(N + 127) / 128, 256, 0, stream>>>(hidden, W_out, b_out,
                                                    (float*)d_out, N, H);
}

// Round 5
// 524.720 us; speedup vs baseline: 1.8575x; 1.2249x over previous
//
#include <hip/hip_runtime.h>

// ---------------------------------------------------------------------------
// GPRGNN forward. R5 == R4 resubmit (R4 bench was GPUAcquisitionTimeout):
//  1. Serial scan_kernel (110us, 1 block) -> 3-phase parallel scan
//     (partial sums / base scan / emit), ~8us.
//  2. agg: paired-edge layout — lanes 0-31 take edge j, lanes 32-63 edge j+1,
//     4 channels/lane; one 512B wave-load covers 2 edges; unroll 4 pairs
//     (8 edges in flight). __shfl_xor(32) merges halves. Skip dead xnext
//     write on last layer.
//  3. bf16 MFMA GEMMs unchanged.
// ---------------------------------------------------------------------------

typedef __attribute__((ext_vector_type(8))) short short8;
typedef __attribute__((ext_vector_type(4))) float f32x4;

__device__ __forceinline__ unsigned short f2bf(float f) {
  union { float f; unsigned u; } c{f};
  unsigned u = c.u;
  return (unsigned short)((u + 0x7fff + ((u >> 16) & 1)) >> 16);  // RNE
}
__device__ __forceinline__ float bf2f_lo(unsigned v) {
  return __uint_as_float(v << 16);
}
__device__ __forceinline__ float bf2f_hi(unsigned v) {
  return __uint_as_float(v & 0xffff0000u);
}
__device__ __forceinline__ unsigned pack2bf(float a, float b) {
  return (unsigned)f2bf(a) | ((unsigned)f2bf(b) << 16);
}

// async global->LDS, 16B per lane (lds dest = wave-uniform base + lane*16)
__device__ __forceinline__ void gll16(const void* g, void* l) {
  __builtin_amdgcn_global_load_lds(
      (const __attribute__((address_space(1))) unsigned int*)g,
      (__attribute__((address_space(3))) unsigned int*)l, 16, 0, 0);
}

// ---------------- CSR build ----------------
__global__ void hist_kernel(const int* __restrict__ dst, int* __restrict__ deg, int E) {
  int e = blockIdx.x * blockDim.x + threadIdx.x;
  if (e < E) atomicAdd(&deg[dst[e]], 1);
}

// phase 1: per-block (1024 elems) partial sums
__global__ __launch_bounds__(256) void scan_partial(const int* __restrict__ deg,
                                                    int* __restrict__ bsum, int N) {
  int b = blockIdx.x, t = threadIdx.x;
  int lane = t & 63, wave = t >> 6;
  int i0 = b * 1024 + t * 4;
  int s = 0;
  if (i0 + 3 < N) {
    int4 v = *(const int4*)&deg[i0];
    s = v.x + v.y + v.z + v.w;
  } else {
    for (int k = 0; k < 4; ++k)
      if (i0 + k < N) s += deg[i0 + k];
  }
  for (int d = 32; d; d >>= 1) s += __shfl_down(s, d, 64);
  __shared__ int ws[4];
  if (lane == 0) ws[wave] = s;
  __syncthreads();
  if (t == 0) bsum[b] = ws[0] + ws[1] + ws[2] + ws[3];
}

// phase 2: one wave scans <=64 block partials -> exclusive base per block
__global__ void scan_base(const int* __restrict__ bsum, int* __restrict__ base, int nb) {
  int l = threadIdx.x;  // 64
  int v = (l < nb) ? bsum[l] : 0;
  int incl = v;
  for (int d = 1; d < 64; d <<= 1) {
    int t = __shfl_up(incl, d, 64);
    if (l >= d) incl += t;
  }
  if (l < nb) base[l] = incl - v;
}

// phase 3: in-block scan + base -> rowptr & cursor
__global__ __launch_bounds__(256) void scan_emit(const int* __restrict__ deg,
                                                 const int* __restrict__ base,
                                                 int* __restrict__ rowptr,
                                                 int* __restrict__ cursor, int N, int E) {
  int b = blockIdx.x, t = threadIdx.x;
  int lane = t & 63, wave = t >> 6;
  int i0 = b * 1024 + t * 4;
  int d0 = 0, d1 = 0, d2 = 0, d3 = 0;
  if (i0 + 3 < N) {
    int4 v = *(const int4*)&deg[i0];
    d0 = v.x; d1 = v.y; d2 = v.z; d3 = v.w;
  } else {
    if (i0 < N) d0 = deg[i0];
    if (i0 + 1 < N) d1 = deg[i0 + 1];
    if (i0 + 2 < N) d2 = deg[i0 + 2];
    if (i0 + 3 < N) d3 = deg[i0 + 3];
  }
  int s = d0 + d1 + d2 + d3;
  int incl = s;
  for (int d = 1; d < 64; d <<= 1) {
    int tv = __shfl_up(incl, d, 64);
    if (lane >= d) incl += tv;
  }
  __shared__ int ws[4];
  if (lane == 63) ws[wave] = incl;
  __syncthreads();
  int woff = 0;
  for (int wv = 0; wv < wave; ++wv) woff += ws[wv];
  int off = base[b] + woff + incl - s;
  if (i0 < N)     { rowptr[i0] = off;                cursor[i0] = off; }
  if (i0 + 1 < N) { int o = off + d0;                rowptr[i0+1] = o; cursor[i0+1] = o; }
  if (i0 + 2 < N) { int o = off + d0 + d1;           rowptr[i0+2] = o; cursor[i0+2] = o; }
  if (i0 + 3 < N) { int o = off + d0 + d1 + d2;      rowptr[i0+3] = o; cursor[i0+3] = o; }
  if (b == 0 && t == 0) rowptr[N] = E;
}

__global__ void fill_kernel(const int* __restrict__ src, const int* __restrict__ dst,
                            const float* __restrict__ w, int* __restrict__ cursor,
                            int* __restrict__ esrc, float* __restrict__ ew, int E) {
  int e = blockIdx.x * blockDim.x + threadIdx.x;
  if (e < E) {
    int d = dst[e];
    int p = atomicAdd(&cursor[d], 1);
    esrc[p] = src[e];
    ew[p] = w[e];
  }
}

// ---------------- weight convert + transpose (once per call, tiny) ----------
__global__ void conv_w_kernel(const float* __restrict__ W_in,
                              const float* __restrict__ Wl,
                              unsigned short* __restrict__ WinT,
                              unsigned short* __restrict__ WlT) {
  int o = blockIdx.x * blockDim.x + threadIdx.x;
  if (o < 65536) {
    int n = o >> 9, k = o & 511;
    WinT[o] = f2bf(W_in[k * 128 + n]);
  } else if (o < 131072) {
    int p = o - 65536;
    int layer = p >> 14, n = (p >> 7) & 127, k = p & 127;
    WlT[p] = f2bf(Wl[layer * 16384 + k * 128 + n]);
  }
}

// ---------------- bf16 MFMA GEMM: C[M][128] = A[M][K] @ B[K][128] + bias ----
template <int K, bool CONV, bool INMODE>
__global__ __launch_bounds__(256) void gemm_bf16(
    const void* __restrict__ Ain, const unsigned short* __restrict__ BT,
    const float* __restrict__ bias, unsigned short* __restrict__ Cb,
    float* __restrict__ hidden, const float* __restrict__ temp, int M) {
  __shared__ unsigned short As[128 * 32];
  __shared__ unsigned short Bs[128 * 32];

  const int tid = threadIdx.x;
  const int lane = tid & 63;
  const int wave = tid >> 6;
  const int wm = (wave & 1) * 64;
  const int wn = (wave >> 1) * 64;
  const int blockRow = blockIdx.x * 128;

  f32x4 acc[4][4];
#pragma unroll
  for (int i = 0; i < 4; ++i)
#pragma unroll
    for (int j = 0; j < 4; ++j) acc[i][j] = (f32x4){0.f, 0.f, 0.f, 0.f};

  for (int k0 = 0; k0 < K; k0 += 32) {
    __syncthreads();
    if (CONV) {
      const float* A = (const float*)Ain;
      int row = tid >> 1;
      int kc = (tid & 1) * 16;
      int grow = blockRow + row;
      if (grow >= M) grow = M - 1;
      const float* s = &A[(size_t)grow * K + k0 + kc];
      float4 v0 = *(const float4*)(s);
      float4 v1 = *(const float4*)(s + 4);
      float4 v2 = *(const float4*)(s + 8);
      float4 v3 = *(const float4*)(s + 12);
      uint4 p0, p1;
      p0.x = pack2bf(v0.x, v0.y); p0.y = pack2bf(v0.z, v0.w);
      p0.z = pack2bf(v1.x, v1.y); p0.w = pack2bf(v1.z, v1.w);
      p1.x = pack2bf(v2.x, v2.y); p1.y = pack2bf(v2.z, v2.w);
      p1.z = pack2bf(v3.x, v3.y); p1.w = pack2bf(v3.z, v3.w);
      *(uint4*)&As[row * 32 + kc] = p0;
      *(uint4*)&As[row * 32 + kc + 8] = p1;
    } else {
      const unsigned short* A = (const unsigned short*)Ain;
#pragma unroll
      for (int ch = wave; ch < 8; ch += 4) {
        int row = ch * 16 + (lane >> 2);
        int grow = blockRow + row;
        if (grow >= M) grow = M - 1;
        gll16(&A[(size_t)grow * K + k0 + (lane & 3) * 8], (char*)As + ch * 1024);
      }
    }
#pragma unroll
    for (int ch = wave; ch < 8; ch += 4) {
      int row = ch * 16 + (lane >> 2);
      gll16(&BT[(size_t)row * K + k0 + (lane & 3) * 8], (char*)Bs + ch * 1024);
    }
    __syncthreads();

    short8 af[4], bfr[4];
#pragma unroll
    for (int i = 0; i < 4; ++i)
      af[i] = *(const short8*)&As[(wm + i * 16 + (lane & 15)) * 32 + (lane >> 4) * 8];
#pragma unroll
    for (int j = 0; j < 4; ++j)
      bfr[j] = *(const short8*)&Bs[(wn + j * 16 + (lane & 15)) * 32 + (lane >> 4) * 8];
#pragma unroll
    for (int i = 0; i < 4; ++i)
#pragma unroll
      for (int j = 0; j < 4; ++j)
        acc[i][j] =
            __builtin_amdgcn_mfma_f32_16x16x32_bf16(af[i], bfr[j], acc[i][j], 0, 0, 0);
  }

  float t0 = INMODE ? temp[0] : 0.f;
#pragma unroll
  for (int j = 0; j < 4; ++j) {
    int col = wn + j * 16 + (lane & 15);
    float bj = bias[col];
#pragma unroll
    for (int i = 0; i < 4; ++i) {
#pragma unroll
      for (int r = 0; r < 4; ++r) {
        int row = blockRow + wm + i * 16 + (lane >> 4) * 4 + r;
        if (row < M) {
          float v = acc[i][j][r] + bj;
          Cb[(size_t)row * 128 + col] = f2bf(v);
          if (INMODE) hidden[(size_t)row * 128 + col] = t0 * v;
        }
      }
    }
  }
}

// ---------------- aggregation: paired-edge, one wave per node ---------------
// lanes 0-31 take even edge of pair, lanes 32-63 odd edge; lane owns channels
// 4*sl..4*sl+3 (8B gather/lane -> 512B wave-load covers 2 edges). Unroll 4
// pairs (8 edges in flight). __shfl_xor(32) merges halves at the end.
__global__ __launch_bounds__(256) void agg_bf16(
    const int* __restrict__ rowptr, const int* __restrict__ esrc,
    const float* __restrict__ ew, const unsigned short* __restrict__ mb,
    unsigned short* __restrict__ xnext, float* __restrict__ hidden,
    const float* __restrict__ temp, int tempidx, int N, int write_x) {
  int node = (int)((blockIdx.x * blockDim.x + threadIdx.x) >> 6);
  int lane = threadIdx.x & 63;
  if (node >= N) return;
  const int half = lane >> 5;
  const int sl = lane & 31;
  int beg = rowptr[node];
  int end = rowptr[node + 1];

  float aA[4] = {0.f, 0.f, 0.f, 0.f}, aB[4] = {0.f, 0.f, 0.f, 0.f};
  float aC[4] = {0.f, 0.f, 0.f, 0.f}, aD[4] = {0.f, 0.f, 0.f, 0.f};

  int j = beg;
  for (; j + 8 <= end; j += 8) {
    int sA = esrc[j + half];     float wA = ew[j + half];
    int sB = esrc[j + 2 + half]; float wB = ew[j + 2 + half];
    int sC = esrc[j + 4 + half]; float wC = ew[j + 4 + half];
    int sD = esrc[j + 6 + half]; float wD = ew[j + 6 + half];
    uint2 vA = *(const uint2*)&mb[(size_t)sA * 128 + sl * 4];
    uint2 vB = *(const uint2*)&mb[(size_t)sB * 128 + sl * 4];
    uint2 vC = *(const uint2*)&mb[(size_t)sC * 128 + sl * 4];
    uint2 vD = *(const uint2*)&mb[(size_t)sD * 128 + sl * 4];
    aA[0] = fmaf(wA, bf2f_lo(vA.x), aA[0]); aA[1] = fmaf(wA, bf2f_hi(vA.x), aA[1]);
    aA[2] = fmaf(wA, bf2f_lo(vA.y), aA[2]); aA[3] = fmaf(wA, bf2f_hi(vA.y), aA[3]);
    aB[0] = fmaf(wB, bf2f_lo(vB.x), aB[0]); aB[1] = fmaf(wB, bf2f_hi(vB.x), aB[1]);
    aB[2] = fmaf(wB, bf2f_lo(vB.y), aB[2]); aB[3] = fmaf(wB, bf2f_hi(vB.y), aB[3]);
    aC[0] = fmaf(wC, bf2f_lo(vC.x), aC[0]); aC[1] = fmaf(wC, bf2f_hi(vC.x), aC[1]);
    aC[2] = fmaf(wC, bf2f_lo(vC.y), aC[2]); aC[3] = fmaf(wC, bf2f_hi(vC.y), aC[3]);
    aD[0] = fmaf(wD, bf2f_lo(vD.x), aD[0]); aD[1] = fmaf(wD, bf2f_hi(vD.x), aD[1]);
    aD[2] = fmaf(wD, bf2f_lo(vD.y), aD[2]); aD[3] = fmaf(wD, bf2f_hi(vD.y), aD[3]);
  }
  for (; j + 2 <= end; j += 2) {
    int s = esrc[j + half];
    float wt = ew[j + half];
    uint2 v = *(const uint2*)&mb[(size_t)s * 128 + sl * 4];
    aA[0] = fmaf(wt, bf2f_lo(v.x), aA[0]); aA[1] = fmaf(wt, bf2f_hi(v.x), aA[1]);
    aA[2] = fmaf(wt, bf2f_lo(v.y), aA[2]); aA[3] = fmaf(wt, bf2f_hi(v.y), aA[3]);
  }
  if (j < end) {  // odd tail: half==1 lanes contribute 0
    int s = esrc[j];
    float wt = half ? 0.f : ew[j];
    uint2 v = *(const uint2*)&mb[(size_t)s * 128 + sl * 4];
    aA[0] = fmaf(wt, bf2f_lo(v.x), aA[0]); aA[1] = fmaf(wt, bf2f_hi(v.x), aA[1]);
    aA[2] = fmaf(wt, bf2f_lo(v.y), aA[2]); aA[3] = fmaf(wt, bf2f_hi(v.y), aA[3]);
  }

  float r[4];
#pragma unroll
  for (int k = 0; k < 4; ++k) {
    float s = (aA[k] + aB[k]) + (aC[k] + aD[k]);
    s += __shfl_xor(s, 32, 64);
    r[k] = fmaxf(s, 0.f);
  }

  if (half == 0) {
    size_t o = (size_t)node * 128 + sl * 4;
    if (write_x) {
      uint2 pk;
      pk.x = pack2bf(r[0], r[1]);
      pk.y = pack2bf(r[2], r[3]);
      *(uint2*)&xnext[o] = pk;
    }
    float tv = temp[tempidx];
    float4 h = *(const float4*)&hidden[o];
    h.x = fmaf(tv, r[0], h.x);
    h.y = fmaf(tv, r[1], h.y);
    h.z = fmaf(tv, r[2], h.z);
    h.w = fmaf(tv, r[3], h.w);
    *(float4*)&hidden[o] = h;
  }
}

// ---------------- fp32 vector GEMM (output projection only) -----------------
__device__ __forceinline__ void fma4(float4& a, float s, const float4& w) {
  a.x = fmaf(s, w.x, a.x);
  a.y = fmaf(s, w.y, a.y);
  a.z = fmaf(s, w.z, a.z);
  a.w = fmaf(s, w.w, a.w);
}

template <int NCOL>
__global__ __launch_bounds__(256) void gemm_f32(
    const float* __restrict__ A, const float* __restrict__ W,
    const float* __restrict__ bias, float* __restrict__ C, int M, int K) {
  constexpr int KT = 64;
  constexpr int CG = NCOL / 8;
  constexpr int RG = 256 / CG;
  constexpr int MROWS = RG * 4;
  constexpr int ACH = MROWS / 4;
  constexpr int WCH = NCOL / 4;

  __shared__ float xs[MROWS * KT];
  __shared__ float wsh[KT * NCOL];

  const int tid = threadIdx.x;
  const int lane = tid & 63;
  const int wave = tid >> 6;
  const int c = tid % CG;
  const int rg = tid / CG;
  const int blockRow = blockIdx.x * MROWS;

  float4 acc0[4], acc1[4];
#pragma unroll
  for (int r = 0; r < 4; ++r) {
    acc0[r] = make_float4(0.f, 0.f, 0.f, 0.f);
    acc1[r] = make_float4(0.f, 0.f, 0.f, 0.f);
  }

  for (int k0 = 0; k0 < K; k0 += KT) {
    __syncthreads();
    for (int ch = wave; ch < ACH; ch += 4) {
      int b = ch * 1024 + lane * 16;
      int row = b >> 8;
      int kb = b & 255;
      int grow = blockRow + row;
      if (grow >= M) grow = M - 1;
      gll16(&A[(size_t)grow * K + k0 + (kb >> 2)], (char*)xs + (size_t)ch * 1024);
    }
    for (int ch = wave; ch < WCH; ch += 4) {
      int b = ch * 1024 + lane * 16;
      int kr = b / (NCOL * 4);
      int cb = b % (NCOL * 4);
      gll16(&W[(size_t)(k0 + kr) * NCOL + (cb >> 2)], (char*)wsh + (size_t)ch * 1024);
    }
    __syncthreads();

#pragma unroll
    for (int k = 0; k < KT; k += 4) {
      float4 av[4];
#pragma unroll
      for (int r = 0; r < 4; ++r)
        av[r] = *reinterpret_cast<const float4*>(&xs[(rg * 4 + r) * KT + k]);
      float4 w0[4], w1[4];
#pragma unroll
      for (int kk = 0; kk < 4; ++kk) {
        w0[kk] = *reinterpret_cast<const float4*>(&wsh[(k + kk) * NCOL + c * 4]);
        w1[kk] = *reinterpret_cast<const float4*>(&wsh[(k + kk) * NCOL + NCOL / 2 + c * 4]);
      }
#pragma unroll
      for (int r = 0; r < 4; ++r) {
        fma4(acc0[r], av[r].x, w0[0]);
        fma4(acc0[r], av[r].y, w0[1]);
        fma4(acc0[r], av[r].z, w0[2]);
        fma4(acc0[r], av[r].w, w0[3]);
        fma4(acc1[r], av[r].x, w1[0]);
        fma4(acc1[r], av[r].y, w1[1]);
        fma4(acc1[r], av[r].z, w1[2]);
        fma4(acc1[r], av[r].w, w1[3]);
      }
    }
  }

  float4 b0 = *reinterpret_cast<const float4*>(&bias[c * 4]);
  float4 b1 = *reinterpret_cast<const float4*>(&bias[NCOL / 2 + c * 4]);
#pragma unroll
  for (int r = 0; r < 4; ++r) {
    int row = blockRow + rg * 4 + r;
    if (row >= M) continue;
    float4 v0 = acc0[r], v1 = acc1[r];
    v0.x += b0.x; v0.y += b0.y; v0.z += b0.z; v0.w += b0.w;
    v1.x += b1.x; v1.y += b1.y; v1.z += b1.z; v1.w += b1.w;
    *reinterpret_cast<float4*>(&C[(size_t)row * NCOL + c * 4]) = v0;
    *reinterpret_cast<float4*>(&C[(size_t)row * NCOL + NCOL / 2 + c * 4]) = v1;
  }
}

extern "C" void kernel_launch(void* const* d_in, const int* in_sizes, int n_in,
                              void* d_out, int out_size, void* d_ws, size_t ws_size,
                              hipStream_t stream) {
  const float* x     = (const float*)d_in[0];
  const float* w     = (const float*)d_in[1];
  const float* W_in  = (const float*)d_in[2];
  const float* b_in  = (const float*)d_in[3];
  const float* Wl    = (const float*)d_in[4];
  const float* bl    = (const float*)d_in[5];
  const float* temp  = (const float*)d_in[6];
  const float* W_out = (const float*)d_in[7];
  const float* b_out = (const float*)d_in[8];
  const int*   src   = (const int*)d_in[9];
  const int*   dst   = (const int*)d_in[10];

  const int IN = 512, H = 128, L = 4;
  const int N = in_sizes[0] / IN;   // 50000
  const int E = in_sizes[1];        // 800000
  const int NB = (N + 1023) / 1024; // 49 (<=64 by construction for this size)

  char* p = (char*)d_ws;
  auto alloc = [&](size_t bytes) {
    void* r = (void*)p;
    p += (bytes + 255) & ~(size_t)255;
    return r;
  };
  unsigned short* xcur_b = (unsigned short*)alloc((size_t)N * H * 2);
  unsigned short* mbuf_b = (unsigned short*)alloc((size_t)N * H * 2);
  float* hidden          = (float*)alloc((size_t)N * H * sizeof(float));
  unsigned short* WinT   = (unsigned short*)alloc((size_t)H * IN * 2);
  unsigned short* WlT    = (unsigned short*)alloc((size_t)L * H * H * 2);
  int*   deg    = (int*)alloc((size_t)N * sizeof(int));
  int*   rowptr = (int*)alloc((size_t)(N + 1) * sizeof(int));
  int*   cursor = (int*)alloc((size_t)N * sizeof(int));
  int*   esrc   = (int*)alloc((size_t)E * sizeof(int));
  float* ew     = (float*)alloc((size_t)E * sizeof(float));
  int*   bsum   = (int*)alloc(64 * sizeof(int));
  int*   base   = (int*)alloc(64 * sizeof(int));

  // ---- CSR build + weight conversion (once per call) ----
  hipMemsetAsync(deg, 0, (size_t)N * sizeof(int), stream);
  hist_kernel<<<(E + 255) / 256, 256, 0, stream>>>(dst, deg, E);
  scan_partial<<<NB, 256, 0, stream>>>(deg, bsum, N);
  scan_base<<<1, 64, 0, stream>>>(bsum, base, NB);
  scan_emit<<<NB, 256, 0, stream>>>(deg, base, rowptr, cursor, N, E);
  fill_kernel<<<(E + 255) / 256, 256, 0, stream>>>(src, dst, w, cursor, esrc, ew, E);
  conv_w_kernel<<<512, 256, 0, stream>>>(W_in, Wl, WinT, WlT);

  const int gB = (N + 127) / 128;  // 391

  // ---- input projection (fused fp32->bf16 conversion of x) ----
  gemm_bf16<512, true, true><<<gB, 256, 0, stream>>>(x, WinT, b_in, xcur_b, hidden,
                                                     temp, N);

  // ---- 4 GPR layers ----
  for (int i = 0; i < L; ++i) {
    gemm_bf16<128, false, false><<<gB, 256, 0, stream>>>(
        xcur_b, WlT + (size_t)i * H * H, bl + (size_t)i * H, mbuf_b, nullptr, temp, N);
    agg_bf16<<<(N + 3) / 4, 256, 0, stream>>>(rowptr, esrc, ew, mbuf_b, xcur_b, hidden,
                                              temp, i + 1, N, (i < L - 1) ? 1 : 0);
  }

  // ---- output projection (fp32 vector) ----
  gemm_f32<64><<<(N + 127) / 128, 256, 0, stream>>>(hidden, W_out, b_out,
                                                    (float*)d_out, N, H);
}